// Round 1
// baseline (8730.403 us; speedup 1.0000x reference)
//
#include <hip/hip_runtime.h>
#include <hip/hip_bf16.h>

#define BS 4
#define SEQL 2048
#define DM 512
#define DIN 1024
#define NH 16
#define HD 64
#define DST 64
#define NC 8
#define CKS 256
#define DIP 2192
#define CVD 1152
#define NROWS (BS*SEQL)          /* 8192 */
#define NTOK (BS*SEQL*DM)        /* 4194304 */

// ---------------- elementwise ----------------
__global__ void k_add_flip(float* __restrict__ dst, const float* __restrict__ src, int flip){
  int i = blockIdx.x*256 + threadIdx.x;
  if(i >= NTOK) return;
  int d = i & (DM-1);
  int l = (i >> 9) & (SEQL-1);
  int b = i >> 20;
  int sl = flip ? (SEQL-1-l) : l;
  dst[i] += src[(b*SEQL + sl)*DM + d];
}

__global__ void k_flip(float* __restrict__ dst, const float* __restrict__ src){
  int i = blockIdx.x*256 + threadIdx.x;
  if(i >= NTOK) return;
  int d = i & (DM-1);
  int l = (i >> 9) & (SEQL-1);
  int b = i >> 20;
  dst[i] = src[(b*SEQL + (SEQL-1-l))*DM + d];
}

// LayerNorm over rows of 512
__global__ void k_ln(const float* __restrict__ X, const float* __restrict__ w,
                     const float* __restrict__ bb, float* __restrict__ O){
  int row = blockIdx.x, tid = threadIdx.x;
  const float* x = X + (size_t)row*DM;
  float* o = O + (size_t)row*DM;
  float s=0.f, s2=0.f;
  for(int j=tid;j<DM;j+=256){ float v=x[j]; s+=v; s2+=v*v; }
  __shared__ float r1[256], r2[256];
  r1[tid]=s; r2[tid]=s2; __syncthreads();
  for(int off=128;off>0;off>>=1){
    if(tid<off){ r1[tid]+=r1[tid+off]; r2[tid]+=r2[tid+off]; }
    __syncthreads();
  }
  float m = r1[0]*(1.f/DM);
  float var = r2[0]*(1.f/DM) - m*m;
  float inv = rsqrtf(var + 1e-5f);
  for(int j=tid;j<DM;j+=256) o[j] = (x[j]-m)*inv*w[j] + bb[j];
}

// RMSNorm over rows of 1024, in place, with gamma
__global__ void k_rms(float* __restrict__ Y, const float* __restrict__ gw){
  int row = blockIdx.x, tid = threadIdx.x;
  float* y = Y + (size_t)row*DIN;
  float ss=0.f;
  for(int j=tid;j<DIN;j+=256){ float v=y[j]; ss+=v*v; }
  __shared__ float red[256];
  red[tid]=ss; __syncthreads();
  for(int off=128;off>0;off>>=1){
    if(tid<off) red[tid]+=red[tid+off];
    __syncthreads();
  }
  float inv = rsqrtf(red[0]*(1.f/DIN) + 1e-5f);
  for(int j=tid;j<DIN;j+=256) y[j] = y[j]*inv*gw[j];
}

// ---------------- GEMM: C = act(A@B + bias) + res ----------------
// A: MxK row-major, B: KxN row-major. M multiple of 64, K multiple of 16.
__global__ void k_gemm(const float* __restrict__ A, const float* __restrict__ B,
                       const float* __restrict__ bias, const float* __restrict__ res,
                       float* __restrict__ C, int M, int N, int K, int act){
  __shared__ float As[64][17];
  __shared__ float Bs[16][65];
  int tx = threadIdx.x, ty = threadIdx.y;
  int tid = ty*16+tx;
  int r0 = blockIdx.y*64, c0 = blockIdx.x*64;
  float acc[4][4];
  #pragma unroll
  for(int i=0;i<4;i++)
    #pragma unroll
    for(int j=0;j<4;j++) acc[i][j]=0.f;
  for(int k0=0;k0<K;k0+=16){
    #pragma unroll
    for(int e=0;e<4;e++){
      int idx = tid + e*256;
      int ar = idx>>4, ac = idx&15;
      As[ar][ac] = A[(size_t)(r0+ar)*K + k0+ac];
      int br = idx>>6, bc = idx&63;
      float bv = 0.f;
      if(c0+bc < N) bv = B[(size_t)(k0+br)*N + c0+bc];
      Bs[br][bc] = bv;
    }
    __syncthreads();
    #pragma unroll
    for(int kk=0;kk<16;kk++){
      float a0=As[ty*4+0][kk],a1=As[ty*4+1][kk],a2=As[ty*4+2][kk],a3=As[ty*4+3][kk];
      float b0=Bs[kk][tx*4+0],b1=Bs[kk][tx*4+1],b2=Bs[kk][tx*4+2],b3=Bs[kk][tx*4+3];
      acc[0][0]+=a0*b0; acc[0][1]+=a0*b1; acc[0][2]+=a0*b2; acc[0][3]+=a0*b3;
      acc[1][0]+=a1*b0; acc[1][1]+=a1*b1; acc[1][2]+=a1*b2; acc[1][3]+=a1*b3;
      acc[2][0]+=a2*b0; acc[2][1]+=a2*b1; acc[2][2]+=a2*b2; acc[2][3]+=a2*b3;
      acc[3][0]+=a3*b0; acc[3][1]+=a3*b1; acc[3][2]+=a3*b2; acc[3][3]+=a3*b3;
    }
    __syncthreads();
  }
  #pragma unroll
  for(int i=0;i<4;i++){
    int r = r0 + ty*4 + i;
    #pragma unroll
    for(int j=0;j<4;j++){
      int c = c0 + tx*4 + j;
      if(c < N){
        float v = acc[i][j];
        if(bias) v += bias[c];
        if(act==1) v = 0.5f*v*(1.f+erff(v*0.70710678118654752f));
        if(res) v += res[(size_t)r*N + c];
        C[(size_t)r*N + c] = v;
      }
    }
  }
}

// ---------------- mamba pieces ----------------
// causal depthwise conv over seq + SiLU.  ZB row stride DIP, xBC at col 1024.
__global__ void k_conv(const float* __restrict__ ZB, const float* __restrict__ cw,
                       const float* __restrict__ cb, float* __restrict__ XC){
  int i = blockIdx.x*256 + threadIdx.x;
  if(i >= BS*SEQL*CVD) return;
  int cch = i % CVD;
  int l = (i / CVD) & (SEQL-1);
  int b = i / (CVD*SEQL);
  float v = cb[cch];
  #pragma unroll
  for(int k=0;k<4;k++){
    int sl = l + k - 3;
    if(sl >= 0) v += ZB[(size_t)(b*SEQL+sl)*DIP + DIN + cch] * cw[cch*4 + k];
  }
  float sig = 1.f/(1.f+expf(-v));
  XC[i] = v*sig;
}

// dt = softplus(raw + dt_bias);  dA = dt * (-exp(A_log))
__global__ void k_dt(const float* __restrict__ ZB, const float* __restrict__ dtb,
                     const float* __restrict__ Alog, float* __restrict__ DT,
                     float* __restrict__ DA){
  int i = blockIdx.x*256 + threadIdx.x;
  if(i >= BS*SEQL*NH) return;
  int h = i & (NH-1);
  int row = i >> 4;
  float raw = ZB[(size_t)row*DIP + (DIN+CVD) + h] + dtb[h];
  float dt = fmaxf(raw,0.f) + log1pf(expf(-fabsf(raw)));
  DT[i] = dt;
  DA[i] = dt * (-expf(Alog[h]));
}

// per (b,c,h): inclusive cumsum of dA within chunk; chunk decay
__global__ void k_acum(const float* __restrict__ DA, float* __restrict__ ACUM,
                       float* __restrict__ CDEC){
  int blk = blockIdx.x;                  // (b*8+c)*16+h
  int h = blk & 15, c = (blk>>4)&7, b = blk>>7;
  int l = threadIdx.x;
  __shared__ float s[256];
  int gl = c*CKS + l;
  s[l] = DA[(size_t)(b*SEQL + gl)*NH + h];
  __syncthreads();
  for(int off=1; off<256; off<<=1){
    float v = (l>=off) ? s[l-off] : 0.f;
    __syncthreads();
    s[l] += v;
    __syncthreads();
  }
  ACUM[(size_t)blk*CKS + l] = s[l];
  if(l==255) CDEC[blk] = expf(s[255]);
}

// Y_diag per (b,c,h,lt): Y[l,p] = sum_{s<=l} (C[l]·B[s]) exp(Ac[l]-Ac[s]) x[s,p]*dt[s]
__global__ void k_ydiag(const float* __restrict__ XC, const float* __restrict__ DT,
                        const float* __restrict__ ACUM, float* __restrict__ Y){
  int blk = blockIdx.x;                  // ((b*8+c)*16+h)*4 + lt
  int lt = blk & 3, h = (blk>>2)&15, c = (blk>>6)&7, b = blk>>9;
  int tid = threadIdx.x;
  int p = tid & 63, lq = tid >> 6;
  __shared__ float Ac[256];
  __shared__ float Bt[32][65];
  __shared__ float Xt[32][65];
  __shared__ float Ct[64][65];
  __shared__ float Gt[64][33];
  const float* xcb = XC + (size_t)b*SEQL*CVD;
  Ac[tid] = ACUM[(size_t)((b*8+c)*16+h)*CKS + tid];
  #pragma unroll
  for(int e=0;e<16;e++){
    int idx = tid + e*256;
    int ll = idx>>6, n = idx&63;
    Ct[ll][n] = xcb[(size_t)(c*CKS + lt*64 + ll)*CVD + (DIN+DST) + n];
  }
  float acc[16];
  #pragma unroll
  for(int j=0;j<16;j++) acc[j]=0.f;
  int ntiles = 2*lt+2;
  for(int st=0; st<ntiles; ++st){
    int s0 = st*32;
    __syncthreads();
    #pragma unroll
    for(int e=0;e<8;e++){
      int idx = tid + e*256;
      int sl = idx>>6, n = idx&63;
      int gs = c*CKS + s0 + sl;
      Bt[sl][n] = xcb[(size_t)gs*CVD + DIN + n];
      Xt[sl][n] = xcb[(size_t)gs*CVD + h*HD + n] * DT[(size_t)(b*SEQL+gs)*NH + h];
    }
    __syncthreads();
    #pragma unroll
    for(int e=0;e<8;e++){
      int idx = tid*8 + e;
      int ll = idx>>5, sp = idx&31;
      int l = lt*64 + ll;
      int sg = s0 + sp;
      float g = 0.f;
      if(sg <= l){
        float dot=0.f;
        #pragma unroll
        for(int n=0;n<64;n++) dot += Ct[ll][n]*Bt[sp][n];
        g = expf(Ac[l]-Ac[sg]) * dot;
      }
      Gt[ll][sp] = g;
    }
    __syncthreads();
    #pragma unroll
    for(int j=0;j<16;j++){
      int ll = lq*16 + j;
      float a = 0.f;
      #pragma unroll
      for(int sp=0;sp<32;sp++) a += Gt[ll][sp]*Xt[sp][p];
      acc[j] += a;
    }
  }
  #pragma unroll
  for(int j=0;j<16;j++){
    int l = lt*64 + lq*16 + j;
    Y[(size_t)(b*SEQL + c*CKS + l)*DIN + h*HD + p] = acc[j];
  }
}

// states per (b,c,h): st[p,n] = sum_l B[l,n] * exp(Ac[255]-Ac[l]) * x[l,p]*dt[l]
__global__ void k_states(const float* __restrict__ XC, const float* __restrict__ DT,
                         const float* __restrict__ ACUM, float* __restrict__ ST){
  int blk = blockIdx.x;                  // (b*8+c)*16+h
  int h = blk & 15, c = (blk>>4)&7, b = blk>>7;
  int tid = threadIdx.x;
  int n = tid & 63, pq = tid >> 6;
  __shared__ float Ac[256];
  __shared__ float Bt[32][64];
  __shared__ float Xt[32][64];
  Ac[tid] = ACUM[(size_t)blk*CKS + tid];
  float acc[16];
  #pragma unroll
  for(int k=0;k<16;k++) acc[k]=0.f;
  const float* xcb = XC + (size_t)b*SEQL*CVD;
  for(int st=0; st<8; ++st){
    __syncthreads();
    #pragma unroll
    for(int e=0;e<8;e++){
      int idx = tid + e*256;
      int sl = idx>>6, nn = idx&63;
      int gs = c*CKS + st*32 + sl;
      Bt[sl][nn] = xcb[(size_t)gs*CVD + DIN + nn];
      float dec = expf(Ac[255] - Ac[st*32+sl]);
      Xt[sl][nn] = xcb[(size_t)gs*CVD + h*HD + nn] * DT[(size_t)(b*SEQL+gs)*NH + h] * dec;
    }
    __syncthreads();
    #pragma unroll
    for(int l=0;l<32;l++){
      float bv = Bt[l][n];
      #pragma unroll
      for(int k=0;k<16;k++) acc[k] += bv * Xt[l][pq + 4*k];
    }
  }
  #pragma unroll
  for(int k=0;k<16;k++){
    int p = pq + 4*k;
    ST[(size_t)blk*4096 + p*64 + n] = acc[k];
  }
}

// inter-chunk scan: prev state entering each chunk
__global__ void k_scan(const float* __restrict__ ST, const float* __restrict__ CDEC,
                       float* __restrict__ PREV){
  int i = blockIdx.x*256 + threadIdx.x;    // BS*NH*4096
  if(i >= BS*NH*4096) return;
  int pn = i & 4095;
  int h = (i>>12) & 15;
  int b = i >> 16;
  float run = 0.f;
  for(int c=0;c<8;c++){
    size_t idx = (size_t)((b*8+c)*16+h)*4096 + pn;
    PREV[idx] = run;
    run = run*CDEC[(b*8+c)*16+h] + ST[idx];
  }
}

// y = (Ydiag + exp(Ac[l]) * C[l]·prev[p,:] + D[h]*xh) * silu(z); in-place on Y
__global__ void k_yfinal(const float* __restrict__ XC, const float* __restrict__ ACUM,
                         const float* __restrict__ PREV, const float* __restrict__ ZB,
                         const float* __restrict__ Dp, float* __restrict__ Y){
  int i = blockIdx.x*256 + threadIdx.x;    // BS*SEQL*DIN
  if(i >= BS*SEQL*DIN) return;
  int p = i & 63;
  int h = (i>>6) & 15;
  int l = (i>>10) & (SEQL-1);
  int b = i >> 21;
  int c = l >> 8;
  int lc = l & 255;
  const float* prev = PREV + (size_t)((b*8+c)*16+h)*4096 + p*64;
  const float* crow = XC + (size_t)(b*SEQL+l)*CVD + (DIN+DST);
  float s = 0.f;
  #pragma unroll
  for(int n=0;n<64;n++) s += crow[n]*prev[n];
  float yoff = expf(ACUM[(size_t)((b*8+c)*16+h)*CKS + lc]) * s;
  float xh = XC[(size_t)(b*SEQL+l)*CVD + h*HD + p];
  float z  = ZB[(size_t)(b*SEQL+l)*DIP + h*HD + p];
  float v = Y[i] + yoff + Dp[h]*xh;
  float sig = 1.f/(1.f+expf(-z));
  Y[i] = v * (z*sig);
}

// ---------------- attention ----------------
__global__ void k_extract(const float* __restrict__ HF, float* __restrict__ QIN,
                          float* __restrict__ CIN){
  int i = blockIdx.x*256 + threadIdx.x;    // BS*1024*DM
  if(i >= BS*1024*DM) return;
  int d = i & (DM-1);
  int q = (i>>9) & 1023;
  int b = i >> 19;
  QIN[i] = HF[(size_t)(b*SEQL + 1024 + q)*DM + d];
  CIN[i] = HF[(size_t)(b*SEQL + q)*DM + d];
}

__global__ void k_attn(const float* __restrict__ Q, const float* __restrict__ K,
                       const float* __restrict__ V, float* __restrict__ O){
  int blk = blockIdx.x;                    // (b*4+h)*1024 + q
  int q = blk & 1023, h = (blk>>10)&3, b = blk>>12;
  int tid = threadIdx.x;
  __shared__ float qrow[128];
  __shared__ float p[1024];
  __shared__ float red[256];
  const float* qptr = Q + (size_t)(b*1024+q)*DM + h*128;
  if(tid < 128) qrow[tid] = qptr[tid];
  __syncthreads();
  const float scale = 0.088388347648318447f;  // 1/sqrt(128)
  float lmax = -1e30f;
  for(int k=tid;k<1024;k+=256){
    const float* kptr = K + (size_t)(b*1024+k)*DM + h*128;
    float s = 0.f;
    for(int d=0;d<128;d++) s += qrow[d]*kptr[d];
    s *= scale;
    p[k] = s;
    lmax = fmaxf(lmax, s);
  }
  red[tid]=lmax; __syncthreads();
  for(int off=128;off>0;off>>=1){
    if(tid<off) red[tid]=fmaxf(red[tid],red[tid+off]);
    __syncthreads();
  }
  float m = red[0];
  __syncthreads();
  float lsum = 0.f;
  for(int k=tid;k<1024;k+=256){ float e=expf(p[k]-m); p[k]=e; lsum+=e; }
  red[tid]=lsum; __syncthreads();
  for(int off=128;off>0;off>>=1){
    if(tid<off) red[tid]+=red[tid+off];
    __syncthreads();
  }
  float inv = 1.f/red[0];
  if(tid < 128){
    int d = tid;
    float acc = 0.f;
    for(int k=0;k<1024;k++) acc += p[k]*V[(size_t)(b*1024+k)*DM + h*128 + d];
    O[(size_t)(b*1024+q)*DM + h*128 + d] = acc*inv;
  }
}

// ---------------- host ----------------
static inline void gemm(hipStream_t st, const float*A, const float*B, const float*bias,
                        const float*res, float*C, int M, int N, int K, int act){
  dim3 g((N+63)/64, M/64), b(16,16);
  k_gemm<<<g,b,0,st>>>(A,B,bias,res,C,M,N,K,act);
}

extern "C" void kernel_launch(void* const* d_in, const int* in_sizes, int n_in,
                              void* d_out, int out_size, void* d_ws, size_t ws_size,
                              hipStream_t stream) {
  (void)in_sizes; (void)n_in; (void)out_size; (void)ws_size;
  const float* x_enc     = (const float*)d_in[0];
  const float* in_proj_w = (const float*)d_in[2];
  const float* conv_w    = (const float*)d_in[3];
  const float* conv_b    = (const float*)d_in[4];
  const float* dt_bias   = (const float*)d_in[5];
  const float* A_log     = (const float*)d_in[6];
  const float* D_param   = (const float*)d_in[7];
  const float* gnorm_w   = (const float*)d_in[8];
  const float* out_proj_w= (const float*)d_in[9];
  const float* norm_w    = (const float*)d_in[10];
  const float* norm_b    = (const float*)d_in[11];
  const float* normf_w   = (const float*)d_in[12];
  const float* normf_b   = (const float*)d_in[13];
  const float* ca_nq_w   = (const float*)d_in[14];
  const float* ca_nq_b   = (const float*)d_in[15];
  const float* ca_nkv_w  = (const float*)d_in[16];
  const float* ca_nkv_b  = (const float*)d_in[17];
  const float* ca_qw     = (const float*)d_in[18];
  const float* ca_kw     = (const float*)d_in[19];
  const float* ca_vw     = (const float*)d_in[20];
  const float* ca_ow     = (const float*)d_in[21];
  const float* ca_qb     = (const float*)d_in[22];
  const float* ca_kb     = (const float*)d_in[23];
  const float* ca_vb     = (const float*)d_in[24];
  const float* ca_ob     = (const float*)d_in[25];
  const float* qp_w      = (const float*)d_in[26];
  const float* qp_b      = (const float*)d_in[27];
  const float* cp_w      = (const float*)d_in[28];
  const float* cp_b      = (const float*)d_in[29];
  const float* dec1_w    = (const float*)d_in[30];
  const float* dec1_b    = (const float*)d_in[31];
  const float* dec2_w    = (const float*)d_in[32];
  const float* dec2_b    = (const float*)d_in[33];

  float* W = (float*)d_ws;
  size_t off = 0;
  auto alloc = [&](size_t n){ float* pp = W + off; off += n; return pp; };
  float* RES  = alloc((size_t)NTOK);
  float* H    = alloc((size_t)NTOK);
  float* HN   = alloc((size_t)NTOK);
  float* HNF  = alloc((size_t)NTOK);
  float* ZB   = alloc((size_t)NROWS*DIP);        // 17,956,864
  float* XC   = alloc((size_t)NROWS*CVD);        //  9,437,184
  float* DT   = alloc((size_t)NROWS*NH);
  float* DA   = alloc((size_t)NROWS*NH);
  float* ACUM = alloc((size_t)BS*NC*NH*CKS);
  float* CDEC = alloc((size_t)BS*NC*NH);
  float* Y    = alloc((size_t)NROWS*DIN);        //  8,388,608
  float* ST   = alloc((size_t)BS*NC*NH*4096);
  float* PREV = alloc((size_t)BS*NC*NH*4096);
  float* YD   = alloc((size_t)NTOK);
  float* HF   = alloc((size_t)NTOK);

  const int TPB = 256;
  const int gTok = (NTOK+TPB-1)/TPB;

  // RES = x_enc
  hipMemcpyAsync(RES, x_enc, (size_t)NTOK*4, hipMemcpyDeviceToDevice, stream);

  for(int layer=0; layer<2; ++layer){
    if(layer>0) k_add_flip<<<gTok,TPB,0,stream>>>(RES, H, 0);
    k_ln<<<NROWS,TPB,0,stream>>>(RES, norm_w + layer*DM, norm_b + layer*DM, HN);
    hipMemsetAsync(H, 0, (size_t)NTOK*4, stream);
    for(int dir=0; dir<2; ++dir){
      const float* U = HN;
      if(dir==1){ k_flip<<<gTok,TPB,0,stream>>>(HNF, HN); U = HNF; }
      int idx = layer*2 + dir;
      const float* Win  = in_proj_w + (size_t)idx*DM*DIP;
      const float* cw   = conv_w   + (size_t)idx*CVD*4;
      const float* cb   = conv_b   + (size_t)idx*CVD;
      const float* dtb  = dt_bias  + (size_t)idx*NH;
      const float* Alog = A_log    + (size_t)idx*NH;
      const float* Dp   = D_param  + (size_t)idx*NH;
      const float* gw   = gnorm_w  + (size_t)idx*DIN;
      const float* Wout = out_proj_w + (size_t)idx*DIN*DM;

      gemm(stream, U, Win, nullptr, nullptr, ZB, NROWS, DIP, DM, 0);
      k_conv<<<(BS*SEQL*CVD+TPB-1)/TPB,TPB,0,stream>>>(ZB, cw, cb, XC);
      k_dt<<<(BS*SEQL*NH+TPB-1)/TPB,TPB,0,stream>>>(ZB, dtb, Alog, DT, DA);
      k_acum<<<BS*NC*NH,256,0,stream>>>(DA, ACUM, CDEC);
      k_ydiag<<<BS*NC*NH*4,256,0,stream>>>(XC, DT, ACUM, Y);
      k_states<<<BS*NC*NH,256,0,stream>>>(XC, DT, ACUM, ST);
      k_scan<<<(BS*NH*4096+TPB-1)/TPB,TPB,0,stream>>>(ST, CDEC, PREV);
      k_yfinal<<<(BS*SEQL*DIN+TPB-1)/TPB,TPB,0,stream>>>(XC, ACUM, PREV, ZB, Dp, Y);
      k_rms<<<NROWS,256,0,stream>>>(Y, gw);
      gemm(stream, Y, Wout, nullptr, nullptr, YD, NROWS, DM, DIN, 0);
      k_add_flip<<<gTok,TPB,0,stream>>>(H, YD, dir);
    }
  }
  k_add_flip<<<gTok,TPB,0,stream>>>(RES, H, 0);
  k_ln<<<NROWS,TPB,0,stream>>>(RES, normf_w, normf_b, HF);

  // ----- attention head (reuse freed buffers) -----
  float* QIN = ZB + 0*2097152;
  float* CIN = ZB + 1*2097152;
  float* QPb = ZB + 2*2097152;
  float* CPb = ZB + 3*2097152;
  float* QN  = ZB + 4*2097152;
  float* CN  = ZB + 5*2097152;
  float* QQ  = ZB + 6*2097152;
  float* KK  = ZB + 7*2097152;
  float* VV  = XC + 0*2097152;
  float* AO  = XC + 1*2097152;
  float* O1  = XC + 2*2097152;
  float* D1  = Y;

  const int M2 = BS*1024;   // 4096
  k_extract<<<(BS*1024*DM+TPB-1)/TPB,TPB,0,stream>>>(HF, QIN, CIN);
  gemm(stream, QIN, qp_w, qp_b, nullptr, QPb, M2, DM, DM, 0);
  gemm(stream, CIN, cp_w, cp_b, nullptr, CPb, M2, DM, DM, 0);
  k_ln<<<M2,TPB,0,stream>>>(QPb, ca_nq_w, ca_nq_b, QN);
  k_ln<<<M2,TPB,0,stream>>>(CPb, ca_nkv_w, ca_nkv_b, CN);
  gemm(stream, QN, ca_qw, ca_qb, nullptr, QQ, M2, DM, DM, 0);
  gemm(stream, CN, ca_kw, ca_kb, nullptr, KK, M2, DM, DM, 0);
  gemm(stream, CN, ca_vw, ca_vb, nullptr, VV, M2, DM, DM, 0);
  k_attn<<<BS*4*1024,256,0,stream>>>(QQ, KK, VV, AO);
  gemm(stream, AO, ca_ow, ca_ob, QPb, O1, M2, DM, DM, 0);
  gemm(stream, O1, dec1_w, dec1_b, nullptr, D1, M2, 1024, DM, 1);
  gemm(stream, D1, dec2_w, dec2_b, nullptr, (float*)d_out, M2, 10, 1024, 0);
}